// Round 9
// baseline (383.012 us; speedup 1.0000x reference)
//
#include <hip/hip_runtime.h>
#include <hip/hip_bf16.h>

// ---------------------------------------------------------------------------
// GNN encoder for MI355X — R12: launch fusion + k_node VALU diet.
//   R11 ledger: k_node 2x67.6=135us, fixed pipeline ~235us (11 launches,
//   several tiny-grid, fully serialized). R12: (a) pack_w1+pack_qd+embed+
//   count+ee+idx fused into ONE k_misc (block-range dispatch, 7535 blocks);
//   flags+deg share one memset; enqueues 13->8. (b) k_node: h pre-split
//   into packed (hi,lo) bf16 u32 at producers (bit-identical hoist of the
//   gather split math); b1 folded into MFMA C-operand. Padded CSR kept.
// ---------------------------------------------------------------------------

#define NN 20000
#define NE 400000

typedef unsigned short u16;
typedef unsigned int   u32;
typedef __attribute__((ext_vector_type(8))) short short8;
typedef __attribute__((ext_vector_type(4))) float f32x4;

__device__ __forceinline__ float bf2f(u16 h) {
  union { u32 u; float f; } v; v.u = ((u32)h) << 16; return v.f;
}
__device__ __forceinline__ u16 f2bf(float f) {
  union { float f; u32 u; } v; v.f = f;
  return (u16)((v.u + 0x7FFFu + ((v.u >> 16) & 1u)) >> 16);
}
// split f32 -> packed (hi<<16)|lo bf16 pair (hi = exact trunc, lo = rounded rest)
__device__ __forceinline__ u32 splitpk(float h) {
  union { float f; u32 u; } uu; uu.f = h;
  u32 hi = uu.u >> 16;
  union { u32 u; float f; } rr; rr.u = hi << 16;
  return (hi << 16) | (u32)f2bf(h - rr.f);
}
__device__ __forceinline__ float ldf(const void* p, size_t i, int f32m) {
  return f32m ? ((const float*)p)[i] : bf2f(((const u16*)p)[i]);
}
__device__ __forceinline__ int ldi(const void* p, size_t i, int i64m) {
  return i64m ? (int)((const long long*)p)[i] : ((const int*)p)[i];
}
__device__ __forceinline__ void stf(void* p, size_t i, float v, int f32m) {
  if (f32m) ((float*)p)[i] = v; else ((u16*)p)[i] = f2bf(v);
}

// --- dtype detection (flags pre-zeroed by memset) --------------------------
__global__ void k_detect(const u16* __restrict__ x16,
                         const int* __restrict__ ei32, int* __restrict__ flags) {
  int t = blockIdx.x * 256 + threadIdx.x;
  int stride = gridDim.x * 256;
  int found_f32 = 0, found_hi = 0;
  for (int i = t; i < NN * 16; i += stride) {
    u16 v = x16[i];
    if ((v & 0x7F80u) == 0x7F80u) found_f32 = 1;  // Inf/NaN pattern: only f32 halves
  }
  for (int i = t; i < 200000; i += stride)
    if (ei32[2 * i + 1] != 0) found_hi = 1;
  if (__any(found_f32) && (threadIdx.x & 63) == 0) atomicOr(&flags[0], 1);
  if (__any(found_hi) && (threadIdx.x & 63) == 0) atomicOr(&flags[1], 1);
}

// --- fused misc: pack_w1 | pack_qd | embed(+split) | count | ee | idx -----
// block ranges: [0,2) w1  [2,34) qd  [34,1284) embed  [1284,2847) count
//               [2847,4410) ee  [4410,7535) idx
__global__ void k_misc(const void* __restrict__ W1, u16* __restrict__ w1p,
                       const void* __restrict__ W2, u16* __restrict__ w2q,
                       u16* __restrict__ w2d,
                       const void* __restrict__ x, const void* __restrict__ Wn,
                       const void* __restrict__ bn, float* __restrict__ h0,
                       u32* __restrict__ h0s,
                       const void* __restrict__ ei, int* __restrict__ deg,
                       const void* __restrict__ ea, const void* __restrict__ We,
                       const void* __restrict__ be, void* __restrict__ out,
                       const int* __restrict__ flags) {
  const int f32m = flags[0], i64m = !flags[1];
  const int b = blockIdx.x, tid = threadIdx.x;
  __shared__ float W[256];
  __shared__ float Bv[16];

  if (b < 2) {                       // ---- pack W1 (512 threads) ----
    int t = b * 256 + tid;
    int lane = t & 63;
    int n = t >> 6;
    int col = n * 16 + (lane & 15), q = lane >> 4;
    for (int j = 0; j < 8; ++j) {
      int kk = q * 8 + j;
      w1p[(size_t)t * 8 + j] = (kk < 16) ? f2bf(ldf(W1, (size_t)kk * 128 + col, f32m)) : (u16)0;
    }
  } else if (b < 34) {               // ---- pack W2 q/d tables ----
    int t = (b - 2) * 256 + tid;
    int lane = t & 63, q = lane >> 4, l16 = lane & 15;
    if (t < 4096) {
      int kc = t >> 6;
#pragma unroll
      for (int jj = 0; jj < 8; ++jj) {
        int kj = kc * 32 + q * 8 + jj;
        int j = kj >> 4, ks = kj & 15;
        w2q[(size_t)t * 8 + jj] =
            f2bf(ldf(W2, (size_t)j * 512 + (16 + ks) * 16 + l16, f32m));
      }
    } else {
      int u = t - 4096;
      int ct = u >> 8;
      int jc = (u >> 6) & 3;
#pragma unroll
      for (int jj = 0; jj < 8; ++jj) {
        int j = jc * 32 + q * 8 + jj;
        w2d[(size_t)u * 8 + jj] =
            f2bf(ldf(W2, (size_t)j * 512 + ct * 16 + l16, f32m));
      }
    }
  } else if (b < 1284) {             // ---- node embedding (+split) ----
    int t = (b - 34) * 256 + tid;
    if (t < NN * 16) {
      int n = t >> 4, d = t & 15;
      float acc = ldf(bn, d, f32m);
      for (int k = 0; k < 16; ++k)
        acc += ldf(x, n * 16 + k, f32m) * ldf(Wn, k * 16 + d, f32m);
      float h = fmaxf(acc, 0.f);
      h0[t] = h;
      h0s[t] = splitpk(h);
    }
  } else if (b < 2847) {             // ---- degree count ----
    int i = (b - 1284) * 256 + tid;
    if (i < NE) atomicAdd(&deg[ldi(ei, NE + i, i64m)], 1);
  } else if (b < 4410) {             // ---- edge embedding + log_softmax ----
    int t = tid;
    W[t] = ldf(We, t, f32m);
    if (t < 16) Bv[t] = ldf(be, t, f32m);
    __syncthreads();
    int e = (b - 2847) * 256 + t;
    if (e >= NE) return;
    float v[16];
    if (f32m) {
      const float4* ep = (const float4*)((const float*)ea + (size_t)e * 16);
      float4 r0 = ep[0], r1 = ep[1], r2 = ep[2], r3 = ep[3];
      v[0]=r0.x; v[1]=r0.y; v[2]=r0.z; v[3]=r0.w;
      v[4]=r1.x; v[5]=r1.y; v[6]=r1.z; v[7]=r1.w;
      v[8]=r2.x; v[9]=r2.y; v[10]=r2.z; v[11]=r2.w;
      v[12]=r3.x; v[13]=r3.y; v[14]=r3.z; v[15]=r3.w;
    } else {
      union { uint4 qv[2]; u16 h[16]; } rw;
      const uint4* ep = (const uint4*)((const u16*)ea + (size_t)e * 16);
      rw.qv[0] = ep[0]; rw.qv[1] = ep[1];
#pragma unroll
      for (int k = 0; k < 16; ++k) v[k] = bf2f(rw.h[k]);
    }
    float o[16];
    float mx = 0.f;
#pragma unroll
    for (int d = 0; d < 16; ++d) {
      float acc = Bv[d];
#pragma unroll
      for (int k = 0; k < 16; ++k) acc += v[k] * W[k * 16 + d];
      acc = fmaxf(acc, 0.f);
      o[d] = acc;
      mx = fmaxf(mx, acc);
    }
    float s = 0.f;
#pragma unroll
    for (int d = 0; d < 16; ++d) s += __expf(o[d] - mx);
    float lse = mx + __logf(s);
    const size_t off_ee = 1120000, off_ls = 7520000;
    if (f32m) {
      union { float4 fv; float f[4]; } pe, pl;
      float* oe = (float*)out + off_ee + (size_t)e * 16;
      float* ol = (float*)out + off_ls + (size_t)e * 16;
#pragma unroll
      for (int g = 0; g < 4; ++g) {
#pragma unroll
        for (int d = 0; d < 4; ++d) { pe.f[d] = o[g*4+d]; pl.f[d] = o[g*4+d] - lse; }
        ((float4*)oe)[g] = pe.fv;
        ((float4*)ol)[g] = pl.fv;
      }
    } else {
      union { uint4 qv[2]; u16 h[16]; } pe, pl;
#pragma unroll
      for (int d = 0; d < 16; ++d) {
        pe.h[d] = f2bf(o[d]);
        pl.h[d] = f2bf(o[d] - lse);
      }
      uint4* oe = (uint4*)((u16*)out + off_ee + (size_t)e * 16);
      uint4* ol = (uint4*)((u16*)out + off_ls + (size_t)e * 16);
      oe[0] = pe.qv[0]; oe[1] = pe.qv[1];
      ol[0] = pl.qv[0]; ol[1] = pl.qv[1];
    }
  } else {                           // ---- edge_index passthrough ----
    int i = (b - 4410) * 256 + tid;
    if (i < 2 * NE) {
      float v = i64m ? (float)((const long long*)ei)[i] : (float)((const int*)ei)[i];
      stf(out, (size_t)320000 + i, v, f32m);
    }
  }
}

// --- pack W2 [128,512] into MFMA B-fragment order (fallback path) ---------
__global__ void k_pack_w2(const void* __restrict__ W2, u16* __restrict__ w2p,
                          const int* __restrict__ flags) {
  const int f32m = flags[0];
  int t = blockIdx.x * 256 + threadIdx.x;          // 32*4*64 = 8192
  if (t >= 32 * 4 * 64) return;
  int lane = t & 63;
  int ks = (t >> 6) & 3;
  int kb = t >> 8;
  int n = lane & 15, q = lane >> 4;
  for (int j = 0; j < 8; ++j) {
    int h = ks * 32 + q * 8 + j;
    w2p[(size_t)t * 8 + j] = f2bf(ldf(W2, (size_t)h * 512 + kb * 16 + n, f32m));
  }
}

// --- pack W1 (fallback path) ----------------------------------------------
__global__ void k_pack_w1(const void* __restrict__ W1, u16* __restrict__ w1p,
                          const int* __restrict__ flags) {
  const int f32m = flags[0];
  int t = blockIdx.x * 256 + threadIdx.x;          // 8*64 = 512
  if (t >= 8 * 64) return;
  int lane = t & 63;
  int n = t >> 6;
  int col = n * 16 + (lane & 15), q = lane >> 4;
  for (int j = 0; j < 8; ++j) {
    int kk = q * 8 + j;
    w1p[(size_t)t * 8 + j] = (kk < 16) ? f2bf(ldf(W1, (size_t)kk * 128 + col, f32m)) : (u16)0;
  }
}

// --- node embedding (fallback path) ---------------------------------------
__global__ void k_embed(const void* __restrict__ x, const void* __restrict__ Wn,
                        const void* __restrict__ bn, float* __restrict__ h0,
                        const int* __restrict__ flags) {
  const int f32m = flags[0];
  int t = blockIdx.x * 256 + threadIdx.x;
  if (t >= NN * 16) return;
  int n = t >> 4, d = t & 15;
  float acc = ldf(bn, d, f32m);
  for (int k = 0; k < 16; ++k)
    acc += ldf(x, n * 16 + k, f32m) * ldf(Wn, k * 16 + d, f32m);
  h0[t] = fmaxf(acc, 0.f);
}

// --- CSR build -------------------------------------------------------------
__global__ void k_count(const void* __restrict__ ei, int* __restrict__ cnt,
                        const int* __restrict__ flags) {
  const int i64m = !flags[1];
  int i = blockIdx.x * 256 + threadIdx.x;
  if (i < NE) atomicAdd(&cnt[ldi(ei, NE + i, i64m)], 1);
}

// old (unpadded) scan — fallback path only; cnt may alias cursor
__global__ void k_scan(const int* __restrict__ cnt, int* __restrict__ rowptr,
                       int* __restrict__ cursor) {
  __shared__ int part[1024];
  int t = threadIdx.x;
  int base = t * 20;                               // 1024*20 = 20480 >= NN
  int s = 0;
  for (int j = 0; j < 20; ++j) { int idx = base + j; if (idx < NN) s += cnt[idx]; }
  part[t] = s;
  __syncthreads();
  for (int off = 1; off < 1024; off <<= 1) {
    int v = (t >= off) ? part[t - off] : 0;
    __syncthreads();
    part[t] += v;
    __syncthreads();
  }
  int run = t ? part[t - 1] : 0;
  for (int j = 0; j < 20; ++j) {
    int idx = base + j;
    if (idx < NN) {
      int c = cnt[idx];                            // read BEFORE cursor aliasing write
      rowptr[idx] = run; cursor[idx] = run; run += c;
    }
  }
  if (t == 1023) rowptr[NN] = part[1023];
}

// padded scan: prow = prefix of (deg+31)&~31 ; deg buffer is separate
__global__ void k_scanp(const int* __restrict__ deg, int* __restrict__ prow,
                        int* __restrict__ cursor) {
  __shared__ int part[1024];
  int t = threadIdx.x;
  int base = t * 20;
  int s = 0;
  for (int j = 0; j < 20; ++j) {
    int idx = base + j;
    if (idx < NN) s += (deg[idx] + 31) & ~31;
  }
  part[t] = s;
  __syncthreads();
  for (int off = 1; off < 1024; off <<= 1) {
    int v = (t >= off) ? part[t - off] : 0;
    __syncthreads();
    part[t] += v;
    __syncthreads();
  }
  int run = t ? part[t - 1] : 0;
  for (int j = 0; j < 20; ++j) {
    int idx = base + j;
    if (idx < NN) {
      int p = (deg[idx] + 31) & ~31;
      prow[idx] = run; cursor[idx] = run; run += p;
    }
  }
  if (t == 1023) prow[NN] = part[1023];
}

// scatter: inv[e]=slot (fallback); srcp[slot]=src; eap[slot]=bf16(ea[e])
__global__ void k_scatter(const void* __restrict__ ei, int* __restrict__ cursor,
                          int* __restrict__ inv, int* __restrict__ srcp,
                          const void* __restrict__ ea, u16* __restrict__ eap,
                          const int* __restrict__ flags) {
  const int f32m = flags[0], i64m = !flags[1];
  int i = blockIdx.x * 256 + threadIdx.x;
  if (i >= NE) return;
  int d = ldi(ei, NE + i, i64m);
  int pos = atomicAdd(&cursor[d], 1);
  if (inv)   inv[i] = pos;
  if (srcp)  srcp[pos] = ldi(ei, i, i64m);
  if (eap) {
    union { uint4 q[2]; u16 h[16]; } o;
    if (f32m) {
      const float4* ep = (const float4*)((const float*)ea + (size_t)i * 16);
      float4 a = ep[0], b = ep[1], c = ep[2], e4 = ep[3];
      o.h[0]=f2bf(a.x);  o.h[1]=f2bf(a.y);  o.h[2]=f2bf(a.z);  o.h[3]=f2bf(a.w);
      o.h[4]=f2bf(b.x);  o.h[5]=f2bf(b.y);  o.h[6]=f2bf(b.z);  o.h[7]=f2bf(b.w);
      o.h[8]=f2bf(c.x);  o.h[9]=f2bf(c.y);  o.h[10]=f2bf(c.z); o.h[11]=f2bf(c.w);
      o.h[12]=f2bf(e4.x); o.h[13]=f2bf(e4.y); o.h[14]=f2bf(e4.z); o.h[15]=f2bf(e4.w);
    } else {
      const uint4* ep = (const uint4*)((const u16*)ea + (size_t)i * 16);
      o.q[0] = ep[0]; o.q[1] = ep[1];
    }
    uint4* dp = (uint4*)(eap + (size_t)pos * 16);
    dp[0] = o.q[0]; dp[1] = o.q[1];
  }
}

// --- per-node fused A2-recompute + T/S/hs MFMA + contraction + combine ----
// Block: 4 nodes, 4 waves (1 node/wave). Padded CSR: each 32-chunk owned by
// exactly one node (beg 32-aligned); pad slots zeroed + A-masked.
// h gathered from pre-split packed (hi,lo) bf16 u32 (hsin).
__launch_bounds__(256)
__attribute__((amdgpu_waves_per_eu(2, 4)))
__global__ void k_node(const int* __restrict__ prow,
                       const int* __restrict__ deg,
                       const int* __restrict__ srcperm,
                       const u16* __restrict__ eap,
                       const float* __restrict__ hin,
                       const u32* __restrict__ hsin,
                       const u16* __restrict__ w1p,
                       const void* __restrict__ b1,
                       const u16* __restrict__ w2q,
                       const u16* __restrict__ w2d,
                       const void* __restrict__ b2,
                       const void* __restrict__ root,
                       const void* __restrict__ bias,
                       float* __restrict__ hout, u32* __restrict__ hsout,
                       void* __restrict__ out,
                       const int* __restrict__ flags) {
  // T_lds element (nb, kj) at byte nb*4096 + kj*2, kj = j*16 + k (j = A2 col,
  // k = h dim), XOR'd on bits 4-6 by ((nb ^ (kj>>5)) & 7) << 4.
  __shared__ u16   T_lds[4 * 2048];     // 16384 B
  __shared__ u32   S_lds[4 * 64];       //  1024 B  (= u16[4][128] row-major)
  __shared__ float hs_lds[4 * 16];      //   256 B
  __shared__ float h_lds[4 * 16];       //   256 B
  __shared__ float part_lds[4 * 256];   //  4096 B  [wave][nrow][d]
  __shared__ float b1_lds[128];         //   512 B
  __shared__ u16   w1_lds[4096];        //  8192 B  W1 B-fragments (shared)
  __shared__ u32   BB_lds[4][320];      //  5120 B  per-wave bounce [16col][20]
  const int f32m = flags[0];
  const int t = threadIdx.x;
  const int lane = t & 63, w = t >> 6;
  const int q = lane >> 4, l16 = lane & 15;
  const int n0 = blockIdx.x * 4;
  const short8 z8 = {0,0,0,0,0,0,0,0};

  if (t < 64) h_lds[t] = hin[(size_t)(n0 + (t >> 4)) * 16 + (t & 15)];
  if (t < 128) b1_lds[t] = ldf(b1, t, f32m);
  {  // copy 8 KB of W1 fragments: layout identical to w1p (n*512 + lane*8)
    const uint4* src = (const uint4*)w1p;
    uint4* dst = (uint4*)w1_lds;
    dst[t] = src[t];
    dst[t + 256] = src[t + 256];
  }

  short8 ONES;
  { union { u32 u[4]; short8 s; } o;
    o.u[0] = 0x3F803F80u; o.u[1] = 0x3F803F80u;
    o.u[2] = 0x3F803F80u; o.u[3] = 0x3F803F80u; ONES = o.s; }

  __syncthreads();                       // b1_lds / w1_lds ready

  const int nb = w;
  {
    const int n  = n0 + nb;
    const int beg = prow[n];             // 32-aligned by construction
    const int end = beg + deg[n];

    f32x4 accT[8];
    float S8[8];
    f32x4 accH = {0.f, 0.f, 0.f, 0.f};
#pragma unroll
    for (int c = 0; c < 8; ++c) {
      accT[c][0] = 0.f; accT[c][1] = 0.f; accT[c][2] = 0.f; accT[c][3] = 0.f;
      S8[c] = 0.f;
    }

    for (int g = beg; g < end; g += 32) {
      int src_l = (lane < 32) ? srcperm[g + lane] : 0;
      union { u32 u[4]; short8 s; } Ahi, Alo, Amk;
#pragma unroll
      for (int jp = 0; jp < 4; ++jp) {
        const int k0 = q * 8 + 2 * jp, k1 = k0 + 1;
        int s0 = __shfl(src_l, k0);
        int s1 = __shfl(src_l, k1);
        u32 v0d = hsin[(size_t)s0 * 16 + l16];
        u32 v1d = hsin[(size_t)s1 * 16 + l16];
        const int v0 = (g + k0 < end);   // g >= beg always (padded CSR)
        const int v1 = (g + k1 < end);
        if (!v0) v0d = 0;
        if (!v1) v1d = 0;
        Ahi.u[jp] = (v0d >> 16) | (v1d & 0xFFFF0000u);
        Alo.u[jp] = (v0d & 0xFFFFu) | (v1d << 16);
        Amk.u[jp] = (v0 ? 0x3F80u : 0u) | (v1 ? 0x3F800000u : 0u);
      }

      // stage-A A-fragments straight from global (L2-resident eap)
      short8 ea0 = z8, ea1 = z8;
      if (q < 2) {
        ea0 = *(const short8*)(eap + (size_t)(g + l16) * 16 + q * 8);
        ea1 = *(const short8*)(eap + (size_t)(g + 16 + l16) * 16 + q * 8);
      }

#pragma unroll
      for (int c = 0; c < 8; ++c) {
        short8 Wf = *(const short8*)&w1_lds[c * 512 + lane * 8];
        // A2[slot][c*16+l16]; b1 rides in the C-operand
        float bb = b1_lds[c * 16 + l16];
        f32x4 ca = {bb, bb, bb, bb}, cb = {bb, bb, bb, bb};
        ca = __builtin_amdgcn_mfma_f32_16x16x32_bf16(ea0, Wf, ca, 0, 0, 0);
        cb = __builtin_amdgcn_mfma_f32_16x16x32_bf16(ea1, Wf, cb, 0, 0, 0);
        u32 p00 = (u32)f2bf(fmaxf(ca[0], 0.f)) |
                  ((u32)f2bf(fmaxf(ca[1], 0.f)) << 16);
        u32 p01 = (u32)f2bf(fmaxf(ca[2], 0.f)) |
                  ((u32)f2bf(fmaxf(ca[3], 0.f)) << 16);
        u32 p10 = (u32)f2bf(fmaxf(cb[0], 0.f)) |
                  ((u32)f2bf(fmaxf(cb[1], 0.f)) << 16);
        u32 p11 = (u32)f2bf(fmaxf(cb[2], 0.f)) |
                  ((u32)f2bf(fmaxf(cb[3], 0.f)) << 16);
        // bounce: BB[col][p] = pack(A2[2p][col], A2[2p+1][col])
        u32* bw = &BB_lds[w][l16 * 20];
        uint2 w0; w0.x = p00; w0.y = p01;
        uint2 w1v; w1v.x = p10; w1v.y = p11;
        *(uint2*)&bw[q * 2]     = w0;     // slot pairs q*2, q*2+1   (s 0-15)
        *(uint2*)&bw[8 + q * 2] = w1v;    // slot pairs 8+q*2, +1    (s 16-31)
        // B-fragment read: lane(q,l16): slots q*8..q*8+7 at this col
        short8 Bf = *(const short8*)&bw[q * 4];
        accT[c] = __builtin_amdgcn_mfma_f32_16x16x32_bf16(Ahi.s, Bf, accT[c], 0, 0, 0);
        accT[c] = __builtin_amdgcn_mfma_f32_16x16x32_bf16(Alo.s, Bf, accT[c], 0, 0, 0);
        f32x4 cs = {0.f, 0.f, 0.f, 0.f};
        cs = __builtin_amdgcn_mfma_f32_16x16x32_bf16(Amk.s, Bf, cs, 0, 0, 0);
        S8[c] += cs[0];
      }
      accH = __builtin_amdgcn_mfma_f32_16x16x32_bf16(Ahi.s, ONES, accH, 0, 0, 0);
      accH = __builtin_amdgcn_mfma_f32_16x16x32_bf16(Alo.s, ONES, accH, 0, 0, 0);
    }

    // ---- dump T (bf16, swizzled), S (bf16), hs (f32) to LDS ----
    {
      char* Tl = (char*)T_lds;
#pragma unroll
      for (int c = 0; c < 8; ++c) {
        // lane (q,l16) holds T[k = q*4+r][j = c*16+l16] in accT[c][r]
        u32 p0 = (u32)f2bf(accT[c][0]) | ((u32)f2bf(accT[c][1]) << 16);
        u32 p1 = (u32)f2bf(accT[c][2]) | ((u32)f2bf(accT[c][3]) << 16);
        int b   = (c * 16 + l16) * 32 + q * 8;
        int key = ((nb ^ (c * 8 + (l16 >> 1))) & 7) << 4;
        uint2 pv; pv.x = p0; pv.y = p1;
        *(uint2*)(Tl + (size_t)nb * 4096 + (b ^ key)) = pv;
      }
      if (q == 0) {
        u16* s16 = (u16*)S_lds;
#pragma unroll
        for (int c = 0; c < 8; ++c)
          s16[nb * 128 + c * 16 + l16] = f2bf(S8[c]);
      }
      if (l16 == 0) *(f32x4*)&hs_lds[nb * 16 + q * 4] = accH;
    }
  }
  __syncthreads();

  // GEMM1 (src half): out_src[16n,16d] += T[n][kj] * w2q[kj][d], K=2048
  // wave w owns kc = w*16 .. w*16+15; only node rows 0..3 valid
  const int row = l16;
  f32x4 c1 = {0.f, 0.f, 0.f, 0.f};
  {
    const short8* w2qf = (const short8*)w2q;
#pragma unroll
    for (int kk = 0; kk < 16; ++kk) {
      int kc = w * 16 + kk;
      int off = ((row & 3) * 4096 + kc * 64 + q * 16) ^ ((((row ^ kc) & 7)) << 4);
      short8 af = *(const short8*)((const char*)T_lds + off);
      if (row >= 4) af = z8;
      short8 bf = w2qf[kc * 64 + lane];
      c1 = __builtin_amdgcn_mfma_f32_16x16x32_bf16(af, bf, c1, 0, 0, 0);
    }
  }
  // GEMM2 (dst half): VS[16n, ct*16+d] = S[n][j] * w2d; wave w owns ct=w*4..+3
  f32x4 c2_0 = {0,0,0,0}, c2_1 = {0,0,0,0}, c2_2 = {0,0,0,0}, c2_3 = {0,0,0,0};
  {
    short8 as0, as1, as2, as3;
    {
      const u32* sb = S_lds + (row & 3) * 64 + q * 4;
      as0 = *(const short8*)(sb + 0);
      as1 = *(const short8*)(sb + 16);
      as2 = *(const short8*)(sb + 32);
      as3 = *(const short8*)(sb + 48);
      if (row >= 4) { as0 = z8; as1 = z8; as2 = z8; as3 = z8; }
    }
    const short8* w2df = (const short8*)w2d;
#pragma unroll
    for (int ci = 0; ci < 4; ++ci) {
      int ct = w * 4 + ci;
      f32x4 cc = {0.f, 0.f, 0.f, 0.f};
      cc = __builtin_amdgcn_mfma_f32_16x16x32_bf16(as0, w2df[(ct * 4 + 0) * 64 + lane], cc, 0, 0, 0);
      cc = __builtin_amdgcn_mfma_f32_16x16x32_bf16(as1, w2df[(ct * 4 + 1) * 64 + lane], cc, 0, 0, 0);
      cc = __builtin_amdgcn_mfma_f32_16x16x32_bf16(as2, w2df[(ct * 4 + 2) * 64 + lane], cc, 0, 0, 0);
      cc = __builtin_amdgcn_mfma_f32_16x16x32_bf16(as3, w2df[(ct * 4 + 3) * 64 + lane], cc, 0, 0, 0);
      if (ci == 0) c2_0 = cc; else if (ci == 1) c2_1 = cc;
      else if (ci == 2) c2_2 = cc; else c2_3 = cc;
    }
  }
  // fold dst half: out_dst[n,d] = sum_ct h[n,ct] * VS[n, ct*16+d]
#pragma unroll
  for (int r = 0; r < 4; ++r) {
    int nrow = q * 4 + r;
    const float* hp = h_lds + (nrow & 3) * 16 + w * 4;
    float a = c1[r];
    a += hp[0] * c2_0[r];
    a += hp[1] * c2_1[r];
    a += hp[2] * c2_2[r];
    a += hp[3] * c2_3[r];
    part_lds[w * 256 + nrow * 16 + l16] = a;
  }
  __syncthreads();

  if (t < 64) {
    int nb2 = t >> 4, d = t & 15;
    int n = n0 + nb2;
    float acc = part_lds[nb2 * 16 + d] + part_lds[256 + nb2 * 16 + d] +
                part_lds[512 + nb2 * 16 + d] + part_lds[768 + nb2 * 16 + d];
    float dg = (float)deg[n];
    acc += ldf(bias, d, f32m);
#pragma unroll
    for (int k = 0; k < 16; ++k) {
      float hv = h_lds[nb2 * 16 + k];
      acc += hv * (ldf(root, (size_t)k * 16 + d, f32m) +
                   dg * ldf(b2, (size_t)k * 16 + d, f32m));
      acc += hs_lds[nb2 * 16 + k] * ldf(b2, (size_t)256 + k * 16 + d, f32m);
    }
    if (hout) {
      hout[(size_t)n * 16 + d] = acc;
      hsout[(size_t)n * 16 + d] = splitpk(acc);
    } else {
      stf(out, (size_t)n * 16 + d, acc, f32m);
    }
  }
}

// --- OLD fused edge kernel (fallback path) --------------------------------
__launch_bounds__(256, 2)
__global__ void k_edge(const void* __restrict__ ea, const void* __restrict__ ei,
                       const float* __restrict__ hprev,
                       const u16* __restrict__ w2p, const u16* __restrict__ w1p,
                       const void* __restrict__ b1, const void* __restrict__ b2,
                       u16* __restrict__ msg16, float* __restrict__ aggr,
                       const int* __restrict__ inv,
                       const int* __restrict__ flags, int use_csr) {
  __shared__ u16   a2_lds[128 * 136];
  __shared__ float nfT[32 * 132];
  __shared__ float msg_lds[128 * 17];
  __shared__ float b1_lds[128];
  __shared__ int   dst_lds[128];

  const int f32m = flags[0], i64m = !flags[1];
  const int t = threadIdx.x;
  const int lane = t & 63, w = t >> 6;
  const int q = lane >> 4, l16 = lane & 15;
  const int e0 = blockIdx.x * 128;

  short8 B[8][4];
  {
    const short8* w2pf = (const short8*)w2p;
#pragma unroll
    for (int i = 0; i < 8; ++i)
#pragma unroll
      for (int ks = 0; ks < 4; ++ks)
        B[i][ks] = w2pf[((w * 8 + i) * 4 + ks) * 64 + lane];
  }
  float b2v[8];
#pragma unroll
  for (int i = 0; i < 8; ++i) b2v[i] = ldf(b2, (w * 8 + i) * 16 + l16, f32m);
  short8 W1f[8];
  {
    const short8* w1pf = (const short8*)w1p;
#pragma unroll
    for (int n = 0; n < 8; ++n) W1f[n] = w1pf[n * 64 + lane];
  }
  if (t < 128) b1_lds[t] = ldf(b1, t, f32m);

  {
    int e = t >> 1, hh = t & 1;
    int node = hh ? ldi(ei, e0 + e, i64m) : ldi(ei, NE + e0 + e, i64m);
    const float4* hp = (const float4*)(hprev + (size_t)node * 16);
    float4 h0v = hp[0], h1v = hp[1], h2v = hp[2], h3v = hp[3];
    float* col = nfT + (size_t)(hh * 16) * 132 + e;
    col[0 * 132] = h0v.x; col[1 * 132] = h0v.y; col[2 * 132] = h0v.z; col[3 * 132] = h0v.w;
    col[4 * 132] = h1v.x; col[5 * 132] = h1v.y; col[6 * 132] = h1v.z; col[7 * 132] = h1v.w;
    col[8 * 132] = h2v.x; col[9 * 132] = h2v.y; col[10 * 132] = h2v.z; col[11 * 132] = h2v.w;
    col[12 * 132] = h3v.x; col[13 * 132] = h3v.y; col[14 * 132] = h3v.z; col[15 * 132] = h3v.w;
    if (!hh) {
      if (use_csr) dst_lds[e] = inv[e0 + e];
      else         dst_lds[e] = node;
    }
    float* mz = msg_lds + e * 17 + hh * 8;
#pragma unroll
    for (int k2 = 0; k2 < 8; ++k2) mz[k2] = 0.f;
  }
  __syncthreads();

#pragma unroll
  for (int mm = 0; mm < 2; ++mm) {
    int m = w * 2 + mm;
    union { short8 s; u16 h[8]; } ua;
    if (q < 2) {
      if (f32m) {
        const float* er = (const float*)ea + ((size_t)(e0 + m * 16 + l16) * 16 + q * 8);
        float4 f0 = *(const float4*)er;
        float4 f1 = *(const float4*)(er + 4);
        ua.h[0] = f2bf(f0.x); ua.h[1] = f2bf(f0.y); ua.h[2] = f2bf(f0.z); ua.h[3] = f2bf(f0.w);
        ua.h[4] = f2bf(f1.x); ua.h[5] = f2bf(f1.y); ua.h[6] = f2bf(f1.z); ua.h[7] = f2bf(f1.w);
      } else {
        ua.s = *(const short8*)((const u16*)ea + ((size_t)(e0 + m * 16 + l16) * 16 + q * 8));
      }
    } else {
#pragma unroll
      for (int j = 0; j < 8; ++j) ua.h[j] = 0;
    }
    short8 A = ua.s;
#pragma unroll
    for (int n = 0; n < 8; ++n) {
      f32x4 c = {0.f, 0.f, 0.f, 0.f};
      c = __builtin_amdgcn_mfma_f32_16x16x32_bf16(A, W1f[n], c, 0, 0, 0);
      float bb = b1_lds[n * 16 + l16];
#pragma unroll
      for (int r = 0; r < 4; ++r)
        a2_lds[(m * 16 + q * 4 + r) * 136 + n * 16 + l16] =
            f2bf(fmaxf(c[r] + bb, 0.f));
    }
  }
  __syncthreads();

#pragma unroll 1
  for (int mi = 0; mi < 8; ++mi) {
    int m = (mi + w * 2) & 7;
    const short8* ap = (const short8*)&a2_lds[(m * 16 + l16) * 136 + q * 8];
    short8 A0 = ap[0], A1 = ap[4], A2f = ap[8], A3 = ap[12];
    float mr0 = 0.f, mr1 = 0.f, mr2 = 0.f, mr3 = 0.f;
#pragma unroll
    for (int i = 0; i < 8; ++i) {
      f32x4 c = {b2v[i], b2v[i], b2v[i], b2v[i]};
      c = __builtin_amdgcn_mfma_f32_16x16x32_bf16(A0, B[i][0], c, 0, 0, 0);
      c = __builtin_amdgcn_mfma_f32_16x16x32_bf16(A1, B[i][1], c, 0, 0, 0);
      c = __builtin_amdgcn_mfma_f32_16x16x32_bf16(A2f, B[i][2], c, 0, 0, 0);
      c = __builtin_amdgcn_mfma_f32_16x16x32_bf16(A3, B[i][3], c, 0, 0, 0);
      int kb = w * 8 + i;
      f32x4 nf4 = *(const f32x4*)&nfT[(size_t)kb * 132 + m * 16 + q * 4];
      mr0 += nf4[0] * c[0];
      mr1 += nf4[1] * c[1];
      mr2 += nf4[2] * c[2];
      mr3 += nf4[3] * c[3];
    }
    int eb = (m * 16 + q * 4) * 17 + l16;
    atomicAdd(&msg_lds[eb + 0 * 17], mr0);
    atomicAdd(&msg_lds[eb + 1 * 17], mr1);
    atomicAdd(&msg_lds[eb + 2 * 17], mr2);
    atomicAdd(&msg_lds[eb + 3 * 17], mr3);
  }
  __syncthreads();

  {
    int e = t >> 1, dh = t & 1;
    const float* mp = msg_lds + e * 17 + dh * 8;
    if (use_csr) {
      int pos = dst_lds[e];
      union { uint4 qv; u16 h[8]; } pk;
#pragma unroll
      for (int dd = 0; dd < 8; ++dd) pk.h[dd] = f2bf(mp[dd]);
      *(uint4*)(msg16 + (size_t)pos * 16 + dh * 8) = pk.qv;
    } else {
      int dnode = dst_lds[e];
      float* ap2 = aggr + (size_t)dnode * 16 + dh * 8;
#pragma unroll
      for (int dd = 0; dd < 8; ++dd) atomicAdd(ap2 + dd, mp[dd]);
    }
  }
}

// --- gather + combine (fallback path) -------------------------------------
__global__ void k_gather(const u16* __restrict__ msg16,
                         const int* __restrict__ rowptr,
                         const float* __restrict__ h_old,
                         const void* __restrict__ root,
                         const void* __restrict__ bias,
                         float* __restrict__ h_new, void* __restrict__ out,
                         const int* __restrict__ flags) {
  const int f32m = flags[0];
  __shared__ float R[256];
  __shared__ float Bv[16];
  int tt = threadIdx.x;
  R[tt] = ldf(root, tt, f32m);
  if (tt < 16) Bv[tt] = ldf(bias, tt, f32m);
  __syncthreads();
  int t = blockIdx.x * 256 + tt;
  if (t >= NN * 16) return;
  int n = t >> 4, d = t & 15;
  float acc = Bv[d];
#pragma unroll
  for (int k = 0; k < 16; ++k) acc += h_old[n * 16 + k] * R[k * 16 + d];
  int beg = rowptr[n], end = rowptr[n + 1];
  for (int i = beg; i < end; ++i)
    acc += bf2f(msg16[(size_t)i * 16 + d]);
  if (h_new) h_new[t] = acc;
  else       stf(out, t, acc, f32m);
}

// --- fallback combine (non-CSR path) --------------------------------------
__global__ void k_combine(const float* __restrict__ h_old,
                          const float* __restrict__ aggr,
                          const void* __restrict__ root,
                          const void* __restrict__ bias,
                          float* __restrict__ h_new, void* __restrict__ out,
                          const int* __restrict__ flags) {
  const int f32m = flags[0];
  int t = blockIdx.x * 256 + threadIdx.x;
  if (t >= NN * 16) return;
  int n = t >> 4, d = t & 15;
  float acc = aggr[t] + ldf(bias, d, f32m);
  for (int k = 0; k < 16; ++k)
    acc += h_old[n * 16 + k] * ldf(root, (size_t)k * 16 + d, f32m);
  if (h_new) h_new[t] = acc;
  else       stf(out, t, acc, f32m);
}

// --- edge embedding + log_softmax (fallback path) -------------------------
__global__ void k_ee(const void* __restrict__ ea, const void* __restrict__ We,
                     const void* __restrict__ be, void* __restrict__ out,
                     const int* __restrict__ flags) {
  const int f32m = flags[0];
  __shared__ float W[256];
  __shared__ float Bv[16];
  int t = threadIdx.x;
  W[t] = ldf(We, t, f32m);
  if (t < 16) Bv[t] = ldf(be, t, f32m);
  __syncthreads();
  int e = blockIdx.x * 256 + t;
  if (e >= NE) return;
  float v[16];
  if (f32m) {
    const float4* ep = (const float4*)((const float*)ea + (size_t)e * 16);
    float4 r0 = ep[0], r1 = ep[1], r2 = ep[2], r3 = ep[3];
    v[0]=r0.x; v[1]=r0.y; v[2]=r0.z; v[3]=r0.w;
    v[4]=r1.x; v[5]=r1.y; v[6]=r1.z; v[7]=r1.w;
    v[8]=r2.x; v[9]=r2.y; v[10]=r2.z; v[11]=r2.w;
    v[12]=r3.x; v[13]=r3.y; v[14]=r3.z; v[15]=r3.w;
  } else {
    union { uint4 qv[2]; u16 h[16]; } rw;
    const uint4* ep = (const uint4*)((const u16*)ea + (size_t)e * 16);
    rw.qv[0] = ep[0]; rw.qv[1] = ep[1];
#pragma unroll
    for (int k = 0; k < 16; ++k) v[k] = bf2f(rw.h[k]);
  }
  float o[16];
  float mx = 0.f;
#pragma unroll
  for (int d = 0; d < 16; ++d) {
    float acc = Bv[d];
#pragma unroll
    for (int k = 0; k < 16; ++k) acc += v[k] * W[k * 16 + d];
    acc = fmaxf(acc, 0.f);
    o[d] = acc;
    mx = fmaxf(mx, acc);
  }
  float s = 0.f;
#pragma unroll
  for (int d = 0; d < 16; ++d) s += __expf(o[d] - mx);
  float lse = mx + __logf(s);
  const size_t off_ee = 1120000, off_ls = 7520000;
  if (f32m) {
    union { float4 fv; float f[4]; } pe, pl;
    float* oe = (float*)out + off_ee + (size_t)e * 16;
    float* ol = (float*)out + off_ls + (size_t)e * 16;
#pragma unroll
    for (int g = 0; g < 4; ++g) {
#pragma unroll
      for (int d = 0; d < 4; ++d) { pe.f[d] = o[g*4+d]; pl.f[d] = o[g*4+d] - lse; }
      ((float4*)oe)[g] = pe.fv;
      ((float4*)ol)[g] = pl.fv;
    }
  } else {
    union { uint4 qv[2]; u16 h[16]; } pe, pl;
#pragma unroll
    for (int d = 0; d < 16; ++d) {
      pe.h[d] = f2bf(o[d]);
      pl.h[d] = f2bf(o[d] - lse);
    }
    uint4* oe = (uint4*)((u16*)out + off_ee + (size_t)e * 16);
    uint4* ol = (uint4*)((u16*)out + off_ls + (size_t)e * 16);
    oe[0] = pe.qv[0]; oe[1] = pe.qv[1];
    ol[0] = pl.qv[0]; ol[1] = pl.qv[1];
  }
}

// --- edge_index passthrough (fallback path) -------------------------------
__global__ void k_idx(const void* __restrict__ ei, void* __restrict__ out,
                      const int* __restrict__ flags) {
  const int f32m = flags[0], i64m = !flags[1];
  int i = blockIdx.x * 256 + threadIdx.x;
  if (i >= 2 * NE) return;
  float v = i64m ? (float)((const long long*)ei)[i] : (float)((const int*)ei)[i];
  stf(out, (size_t)320000 + i, v, f32m);
}

extern "C" void kernel_launch(void* const* d_in, const int* in_sizes, int n_in,
                              void* d_out, int out_size, void* d_ws, size_t ws_size,
                              hipStream_t stream) {
  const void* x     = d_in[0];
  const void* ei    = d_in[1];
  const void* ea    = d_in[2];
  const void* Wn    = d_in[3];
  const void* bn    = d_in[4];
  const void* We    = d_in[5];
  const void* be    = d_in[6];
  const void* W1    = d_in[7];
  const void* b1    = d_in[8];
  const void* W2    = d_in[9];
  const void* b2    = d_in[10];
  const void* root1 = d_in[11];
  const void* bias1 = d_in[12];
  const void* root2 = d_in[13];
  const void* bias2 = d_in[14];

  char* ws = (char*)d_ws;
  const size_t need_new = 42219296;

  if (ws_size >= need_new) {
    int*   flags   = (int*)ws;                        // @0          16
    int*   deg     = (int*)(ws + 16);                 // 80,000  (memset with flags)
    float* h0      = (float*)(ws + 80016);            // 1,280,000
    u32*   h0s     = (u32*)(ws + 1360016);            // 1,280,000
    float* h1      = (float*)(ws + 2640016);          // 1,280,000
    u32*   h1s     = (u32*)(ws + 3920016);            // 1,280,000
    u16*   w1p     = (u16*)(ws + 5200016);            // 8,192
    u16*   w2q     = (u16*)(ws + 5208208);            // 65,536
    u16*   w2d     = (u16*)(ws + 5273744);            // 65,536
    int*   prow    = (int*)(ws + 5339280);            // 80,016
    int*   cursor  = (int*)(ws + 5419296);            // 80,000
    int*   srcperm = (int*)(ws + 5499296);            // 4,080,000 (1.02M slots)
    u16*   eap     = (u16*)(ws + 9579296);            // 32,640,000

    hipMemsetAsync(ws, 0, 80016, stream);             // flags + deg
    hipMemsetAsync(srcperm, 0, 36720000, stream);     // srcperm + eap (pad slots)
    k_detect<<<128, 256, 0, stream>>>((const u16*)x, (const int*)ei, flags);
    k_misc<<<7535, 256, 0, stream>>>(W1, w1p, W2, w2q, w2d, x, Wn, bn, h0, h0s,
                                     ei, deg, ea, We, be, d_out, flags);
    k_scanp<<<1, 1024, 0, stream>>>(deg, prow, cursor);
    k_scatter<<<1563, 256, 0, stream>>>(ei, cursor, nullptr, srcperm, ea, eap, flags);

    k_node<<<5000, 256, 0, stream>>>(prow, deg, srcperm, eap, h0, h0s, w1p, b1,
                                     w2q, w2d, b2, root1, bias1, h1, h1s, nullptr, flags);
    k_node<<<5000, 256, 0, stream>>>(prow, deg, srcperm, eap, h1, h1s, w1p, b1,
                                     w2q, w2d, b2, root2, bias2, nullptr, nullptr, d_out, flags);
    return;
  }

  // ---------------- fallback: previous-session pipeline -------------------
  int*   flags  = (int*)ws;                              // @0, 16 B
  float* h0     = (float*)(ws + 16);                     // 1,280,000 B
  float* h1     = (float*)(ws + 1280016);                // 1,280,000 B
  u16*   w2p    = (u16*)(ws + 2560016);                  //   131,072 B
  u16*   w1p    = (u16*)(ws + 2691088);                  //     8,192 B
  u16*   msg16  = (u16*)(ws + 2699280);                  // 12,800,000 B
  int*   rowptr = (int*)(ws + 15499280);                 //     80,016 B
  int*   cursor = (int*)(ws + 15579296);                 //     80,000 B
  int*   inv    = (int*)(ws + 15659296);                 //  1,600,000 B
  const size_t need_csr = 17259296;
  float* aggr = (float*)(ws + 2699280);                  // aliases msg16
  const int use_csr = (ws_size >= need_csr) ? 1 : 0;

  hipMemsetAsync(flags, 0, 16, stream);
  k_detect<<<64, 256, 0, stream>>>((const u16*)x, (const int*)ei, flags);
  k_pack_w2<<<32, 256, 0, stream>>>(W2, w2p, flags);
  k_pack_w1<<<2, 256, 0, stream>>>(W1, w1p, flags);
  k_embed<<<1250, 256, 0, stream>>>(x, Wn, bn, h0, flags);

  if (use_csr) {
    hipMemsetAsync(cursor, 0, NN * 4, stream);
    k_count<<<1563, 256, 0, stream>>>(ei, cursor, flags);
    k_scan<<<1, 1024, 0, stream>>>(cursor, rowptr, cursor);
    k_scatter<<<1563, 256, 0, stream>>>(ei, cursor, inv, nullptr, nullptr, nullptr, flags);

    k_edge<<<3125, 256, 0, stream>>>(ea, ei, h0, w2p, w1p, b1, b2, msg16, nullptr, inv, flags, 1);
    k_gather<<<1250, 256, 0, stream>>>(msg16, rowptr, h0, root1, bias1, h1, nullptr, flags);
    k_edge<<<3125, 256, 0, stream>>>(ea, ei, h1, w2p, w1p, b1, b2, msg16, nullptr, inv, flags, 1);
    k_gather<<<1250, 256, 0, stream>>>(msg16, rowptr, h1, root2, bias2, nullptr, d_out, flags);
  } else {
    hipMemsetAsync(aggr, 0, (size_t)NN * 16 * 4, stream);
    k_edge<<<3125, 256, 0, stream>>>(ea, ei, h0, w2p, w1p, b1, b2, nullptr, aggr, nullptr, flags, 0);
    k_combine<<<1250, 256, 0, stream>>>(h0, aggr, root1, bias1, h1, nullptr, flags);
    hipMemsetAsync(aggr, 0, (size_t)NN * 16 * 4, stream);
    k_edge<<<3125, 256, 0, stream>>>(ea, ei, h1, w2p, w1p, b1, b2, nullptr, aggr, nullptr, flags, 0);
    k_combine<<<1250, 256, 0, stream>>>(h1, aggr, root2, bias2, nullptr, d_out, flags);
  }

  k_ee<<<1563, 256, 0, stream>>>(ea, We, be, d_out, flags);
  k_idx<<<3125, 256, 0, stream>>>(ei, d_out, flags);
}

// Round 10
// 353.507 us; speedup vs baseline: 1.0835x; 1.0835x over previous
//
#include <hip/hip_runtime.h>
#include <hip/hip_bf16.h>

// ---------------------------------------------------------------------------
// GNN encoder for MI355X — R13: keep launch fusion, revert k_node diet.
//   R12 ledger split: fusion saved ~20us (remainder 235->215) but the
//   hsin/b1-in-C "VALU diet" cost +16.5us/launch (VGPR 84->116, occupancy
//   24->17% -> latency-bound loop lost wave overlap). R13: k_node is the
//   R11-verified version (67.6us, VGPR 84); k_misc fusion kept (no h0s).
// ---------------------------------------------------------------------------

#define NN 20000
#define NE 400000

typedef unsigned short u16;
typedef unsigned int   u32;
typedef __attribute__((ext_vector_type(8))) short short8;
typedef __attribute__((ext_vector_type(4))) float f32x4;

__device__ __forceinline__ float bf2f(u16 h) {
  union { u32 u; float f; } v; v.u = ((u32)h) << 16; return v.f;
}
__device__ __forceinline__ u16 f2bf(float f) {
  union { float f; u32 u; } v; v.f = f;
  return (u16)((v.u + 0x7FFFu + ((v.u >> 16) & 1u)) >> 16);
}
__device__ __forceinline__ float ldf(const void* p, size_t i, int f32m) {
  return f32m ? ((const float*)p)[i] : bf2f(((const u16*)p)[i]);
}
__device__ __forceinline__ int ldi(const void* p, size_t i, int i64m) {
  return i64m ? (int)((const long long*)p)[i] : ((const int*)p)[i];
}
__device__ __forceinline__ void stf(void* p, size_t i, float v, int f32m) {
  if (f32m) ((float*)p)[i] = v; else ((u16*)p)[i] = f2bf(v);
}

// --- dtype detection (flags pre-zeroed by memset) --------------------------
__global__ void k_detect(const u16* __restrict__ x16,
                         const int* __restrict__ ei32, int* __restrict__ flags) {
  int t = blockIdx.x * 256 + threadIdx.x;
  int stride = gridDim.x * 256;
  int found_f32 = 0, found_hi = 0;
  for (int i = t; i < NN * 16; i += stride) {
    u16 v = x16[i];
    if ((v & 0x7F80u) == 0x7F80u) found_f32 = 1;  // Inf/NaN pattern: only f32 halves
  }
  for (int i = t; i < 200000; i += stride)
    if (ei32[2 * i + 1] != 0) found_hi = 1;
  if (__any(found_f32) && (threadIdx.x & 63) == 0) atomicOr(&flags[0], 1);
  if (__any(found_hi) && (threadIdx.x & 63) == 0) atomicOr(&flags[1], 1);
}

// --- fused misc: pack_w1 | pack_qd | embed | count | ee | idx -------------
// block ranges: [0,2) w1  [2,34) qd  [34,1284) embed  [1284,2847) count
//               [2847,4410) ee  [4410,7535) idx
__global__ void k_misc(const void* __restrict__ W1, u16* __restrict__ w1p,
                       const void* __restrict__ W2, u16* __restrict__ w2q,
                       u16* __restrict__ w2d,
                       const void* __restrict__ x, const void* __restrict__ Wn,
                       const void* __restrict__ bn, float* __restrict__ h0,
                       const void* __restrict__ ei, int* __restrict__ deg,
                       const void* __restrict__ ea, const void* __restrict__ We,
                       const void* __restrict__ be, void* __restrict__ out,
                       const int* __restrict__ flags) {
  const int f32m = flags[0], i64m = !flags[1];
  const int b = blockIdx.x, tid = threadIdx.x;
  __shared__ float W[256];
  __shared__ float Bv[16];

  if (b < 2) {                       // ---- pack W1 (512 threads) ----
    int t = b * 256 + tid;
    int lane = t & 63;
    int n = t >> 6;
    int col = n * 16 + (lane & 15), q = lane >> 4;
    for (int j = 0; j < 8; ++j) {
      int kk = q * 8 + j;
      w1p[(size_t)t * 8 + j] = (kk < 16) ? f2bf(ldf(W1, (size_t)kk * 128 + col, f32m)) : (u16)0;
    }
  } else if (b < 34) {               // ---- pack W2 q/d tables ----
    int t = (b - 2) * 256 + tid;
    int lane = t & 63, q = lane >> 4, l16 = lane & 15;
    if (t < 4096) {
      int kc = t >> 6;
#pragma unroll
      for (int jj = 0; jj < 8; ++jj) {
        int kj = kc * 32 + q * 8 + jj;
        int j = kj >> 4, ks = kj & 15;
        w2q[(size_t)t * 8 + jj] =
            f2bf(ldf(W2, (size_t)j * 512 + (16 + ks) * 16 + l16, f32m));
      }
    } else {
      int u = t - 4096;
      int ct = u >> 8;
      int jc = (u >> 6) & 3;
#pragma unroll
      for (int jj = 0; jj < 8; ++jj) {
        int j = jc * 32 + q * 8 + jj;
        w2d[(size_t)u * 8 + jj] =
            f2bf(ldf(W2, (size_t)j * 512 + ct * 16 + l16, f32m));
      }
    }
  } else if (b < 1284) {             // ---- node embedding ----
    int t = (b - 34) * 256 + tid;
    if (t < NN * 16) {
      int n = t >> 4, d = t & 15;
      float acc = ldf(bn, d, f32m);
      for (int k = 0; k < 16; ++k)
        acc += ldf(x, n * 16 + k, f32m) * ldf(Wn, k * 16 + d, f32m);
      h0[t] = fmaxf(acc, 0.f);
    }
  } else if (b < 2847) {             // ---- degree count ----
    int i = (b - 1284) * 256 + tid;
    if (i < NE) atomicAdd(&deg[ldi(ei, NE + i, i64m)], 1);
  } else if (b < 4410) {             // ---- edge embedding + log_softmax ----
    int t = tid;
    W[t] = ldf(We, t, f32m);
    if (t < 16) Bv[t] = ldf(be, t, f32m);
    __syncthreads();
    int e = (b - 2847) * 256 + t;
    if (e >= NE) return;
    float v[16];
    if (f32m) {
      const float4* ep = (const float4*)((const float*)ea + (size_t)e * 16);
      float4 r0 = ep[0], r1 = ep[1], r2 = ep[2], r3 = ep[3];
      v[0]=r0.x; v[1]=r0.y; v[2]=r0.z; v[3]=r0.w;
      v[4]=r1.x; v[5]=r1.y; v[6]=r1.z; v[7]=r1.w;
      v[8]=r2.x; v[9]=r2.y; v[10]=r2.z; v[11]=r2.w;
      v[12]=r3.x; v[13]=r3.y; v[14]=r3.z; v[15]=r3.w;
    } else {
      union { uint4 qv[2]; u16 h[16]; } rw;
      const uint4* ep = (const uint4*)((const u16*)ea + (size_t)e * 16);
      rw.qv[0] = ep[0]; rw.qv[1] = ep[1];
#pragma unroll
      for (int k = 0; k < 16; ++k) v[k] = bf2f(rw.h[k]);
    }
    float o[16];
    float mx = 0.f;
#pragma unroll
    for (int d = 0; d < 16; ++d) {
      float acc = Bv[d];
#pragma unroll
      for (int k = 0; k < 16; ++k) acc += v[k] * W[k * 16 + d];
      acc = fmaxf(acc, 0.f);
      o[d] = acc;
      mx = fmaxf(mx, acc);
    }
    float s = 0.f;
#pragma unroll
    for (int d = 0; d < 16; ++d) s += __expf(o[d] - mx);
    float lse = mx + __logf(s);
    const size_t off_ee = 1120000, off_ls = 7520000;
    if (f32m) {
      union { float4 fv; float f[4]; } pe, pl;
      float* oe = (float*)out + off_ee + (size_t)e * 16;
      float* ol = (float*)out + off_ls + (size_t)e * 16;
#pragma unroll
      for (int g = 0; g < 4; ++g) {
#pragma unroll
        for (int d = 0; d < 4; ++d) { pe.f[d] = o[g*4+d]; pl.f[d] = o[g*4+d] - lse; }
        ((float4*)oe)[g] = pe.fv;
        ((float4*)ol)[g] = pl.fv;
      }
    } else {
      union { uint4 qv[2]; u16 h[16]; } pe, pl;
#pragma unroll
      for (int d = 0; d < 16; ++d) {
        pe.h[d] = f2bf(o[d]);
        pl.h[d] = f2bf(o[d] - lse);
      }
      uint4* oe = (uint4*)((u16*)out + off_ee + (size_t)e * 16);
      uint4* ol = (uint4*)((u16*)out + off_ls + (size_t)e * 16);
      oe[0] = pe.qv[0]; oe[1] = pe.qv[1];
      ol[0] = pl.qv[0]; ol[1] = pl.qv[1];
    }
  } else {                           // ---- edge_index passthrough ----
    int i = (b - 4410) * 256 + tid;
    if (i < 2 * NE) {
      float v = i64m ? (float)((const long long*)ei)[i] : (float)((const int*)ei)[i];
      stf(out, (size_t)320000 + i, v, f32m);
    }
  }
}

// --- pack W2 [128,512] into MFMA B-fragment order (fallback path) ---------
__global__ void k_pack_w2(const void* __restrict__ W2, u16* __restrict__ w2p,
                          const int* __restrict__ flags) {
  const int f32m = flags[0];
  int t = blockIdx.x * 256 + threadIdx.x;          // 32*4*64 = 8192
  if (t >= 32 * 4 * 64) return;
  int lane = t & 63;
  int ks = (t >> 6) & 3;
  int kb = t >> 8;
  int n = lane & 15, q = lane >> 4;
  for (int j = 0; j < 8; ++j) {
    int h = ks * 32 + q * 8 + j;
    w2p[(size_t)t * 8 + j] = f2bf(ldf(W2, (size_t)h * 512 + kb * 16 + n, f32m));
  }
}

// --- pack W1 (fallback path) ----------------------------------------------
__global__ void k_pack_w1(const void* __restrict__ W1, u16* __restrict__ w1p,
                          const int* __restrict__ flags) {
  const int f32m = flags[0];
  int t = blockIdx.x * 256 + threadIdx.x;          // 8*64 = 512
  if (t >= 8 * 64) return;
  int lane = t & 63;
  int n = t >> 6;
  int col = n * 16 + (lane & 15), q = lane >> 4;
  for (int j = 0; j < 8; ++j) {
    int kk = q * 8 + j;
    w1p[(size_t)t * 8 + j] = (kk < 16) ? f2bf(ldf(W1, (size_t)kk * 128 + col, f32m)) : (u16)0;
  }
}

// --- node embedding (fallback path) ---------------------------------------
__global__ void k_embed(const void* __restrict__ x, const void* __restrict__ Wn,
                        const void* __restrict__ bn, float* __restrict__ h0,
                        const int* __restrict__ flags) {
  const int f32m = flags[0];
  int t = blockIdx.x * 256 + threadIdx.x;
  if (t >= NN * 16) return;
  int n = t >> 4, d = t & 15;
  float acc = ldf(bn, d, f32m);
  for (int k = 0; k < 16; ++k)
    acc += ldf(x, n * 16 + k, f32m) * ldf(Wn, k * 16 + d, f32m);
  h0[t] = fmaxf(acc, 0.f);
}

// --- CSR build -------------------------------------------------------------
__global__ void k_count(const void* __restrict__ ei, int* __restrict__ cnt,
                        const int* __restrict__ flags) {
  const int i64m = !flags[1];
  int i = blockIdx.x * 256 + threadIdx.x;
  if (i < NE) atomicAdd(&cnt[ldi(ei, NE + i, i64m)], 1);
}

// old (unpadded) scan — fallback path only; cnt may alias cursor
__global__ void k_scan(const int* __restrict__ cnt, int* __restrict__ rowptr,
                       int* __restrict__ cursor) {
  __shared__ int part[1024];
  int t = threadIdx.x;
  int base = t * 20;                               // 1024*20 = 20480 >= NN
  int s = 0;
  for (int j = 0; j < 20; ++j) { int idx = base + j; if (idx < NN) s += cnt[idx]; }
  part[t] = s;
  __syncthreads();
  for (int off = 1; off < 1024; off <<= 1) {
    int v = (t >= off) ? part[t - off] : 0;
    __syncthreads();
    part[t] += v;
    __syncthreads();
  }
  int run = t ? part[t - 1] : 0;
  for (int j = 0; j < 20; ++j) {
    int idx = base + j;
    if (idx < NN) {
      int c = cnt[idx];                            // read BEFORE cursor aliasing write
      rowptr[idx] = run; cursor[idx] = run; run += c;
    }
  }
  if (t == 1023) rowptr[NN] = part[1023];
}

// padded scan: prow = prefix of (deg+31)&~31 ; deg buffer is separate
__global__ void k_scanp(const int* __restrict__ deg, int* __restrict__ prow,
                        int* __restrict__ cursor) {
  __shared__ int part[1024];
  int t = threadIdx.x;
  int base = t * 20;
  int s = 0;
  for (int j = 0; j < 20; ++j) {
    int idx = base + j;
    if (idx < NN) s += (deg[idx] + 31) & ~31;
  }
  part[t] = s;
  __syncthreads();
  for (int off = 1; off < 1024; off <<= 1) {
    int v = (t >= off) ? part[t - off] : 0;
    __syncthreads();
    part[t] += v;
    __syncthreads();
  }
  int run = t ? part[t - 1] : 0;
  for (int j = 0; j < 20; ++j) {
    int idx = base + j;
    if (idx < NN) {
      int p = (deg[idx] + 31) & ~31;
      prow[idx] = run; cursor[idx] = run; run += p;
    }
  }
  if (t == 1023) prow[NN] = part[1023];
}

// scatter: inv[e]=slot (fallback); srcp[slot]=src; eap[slot]=bf16(ea[e])
__global__ void k_scatter(const void* __restrict__ ei, int* __restrict__ cursor,
                          int* __restrict__ inv, int* __restrict__ srcp,
                          const void* __restrict__ ea, u16* __restrict__ eap,
                          const int* __restrict__ flags) {
  const int f32m = flags[0], i64m = !flags[1];
  int i = blockIdx.x * 256 + threadIdx.x;
  if (i >= NE) return;
  int d = ldi(ei, NE + i, i64m);
  int pos = atomicAdd(&cursor[d], 1);
  if (inv)   inv[i] = pos;
  if (srcp)  srcp[pos] = ldi(ei, i, i64m);
  if (eap) {
    union { uint4 q[2]; u16 h[16]; } o;
    if (f32m) {
      const float4* ep = (const float4*)((const float*)ea + (size_t)i * 16);
      float4 a = ep[0], b = ep[1], c = ep[2], e4 = ep[3];
      o.h[0]=f2bf(a.x);  o.h[1]=f2bf(a.y);  o.h[2]=f2bf(a.z);  o.h[3]=f2bf(a.w);
      o.h[4]=f2bf(b.x);  o.h[5]=f2bf(b.y);  o.h[6]=f2bf(b.z);  o.h[7]=f2bf(b.w);
      o.h[8]=f2bf(c.x);  o.h[9]=f2bf(c.y);  o.h[10]=f2bf(c.z); o.h[11]=f2bf(c.w);
      o.h[12]=f2bf(e4.x); o.h[13]=f2bf(e4.y); o.h[14]=f2bf(e4.z); o.h[15]=f2bf(e4.w);
    } else {
      const uint4* ep = (const uint4*)((const u16*)ea + (size_t)i * 16);
      o.q[0] = ep[0]; o.q[1] = ep[1];
    }
    uint4* dp = (uint4*)(eap + (size_t)pos * 16);
    dp[0] = o.q[0]; dp[1] = o.q[1];
  }
}

// --- per-node fused A2-recompute + T/S/hs MFMA + contraction + combine ----
// Block: 4 nodes, 4 waves (1 node/wave). Padded CSR: each 32-chunk owned by
// exactly one node (beg 32-aligned); pad slots zeroed + A-masked.
// (R11-verified version: VGPR 84, 67.6us)
__launch_bounds__(256)
__attribute__((amdgpu_waves_per_eu(2, 4)))
__global__ void k_node(const int* __restrict__ prow,
                       const int* __restrict__ deg,
                       const int* __restrict__ srcperm,
                       const u16* __restrict__ eap,
                       const float* __restrict__ hin,
                       const u16* __restrict__ w1p,
                       const void* __restrict__ b1,
                       const u16* __restrict__ w2q,
                       const u16* __restrict__ w2d,
                       const void* __restrict__ b2,
                       const void* __restrict__ root,
                       const void* __restrict__ bias,
                       float* __restrict__ hout, void* __restrict__ out,
                       const int* __restrict__ flags) {
  // T_lds element (nb, kj) at byte nb*4096 + kj*2, kj = j*16 + k (j = A2 col,
  // k = h dim), XOR'd on bits 4-6 by ((nb ^ (kj>>5)) & 7) << 4.
  __shared__ u16   T_lds[4 * 2048];     // 16384 B
  __shared__ u32   S_lds[4 * 64];       //  1024 B  (= u16[4][128] row-major)
  __shared__ float hs_lds[4 * 16];      //   256 B
  __shared__ float h_lds[4 * 16];       //   256 B
  __shared__ float part_lds[4 * 256];   //  4096 B  [wave][nrow][d]
  __shared__ float b1_lds[128];         //   512 B
  __shared__ u16   w1_lds[4096];        //  8192 B  W1 B-fragments (shared)
  __shared__ u32   BB_lds[4][320];      //  5120 B  per-wave bounce [16col][20]
  const int f32m = flags[0];
  const int t = threadIdx.x;
  const int lane = t & 63, w = t >> 6;
  const int q = lane >> 4, l16 = lane & 15;
  const int n0 = blockIdx.x * 4;
  const short8 z8 = {0,0,0,0,0,0,0,0};

  if (t < 64) h_lds[t] = hin[(size_t)(n0 + (t >> 4)) * 16 + (t & 15)];
  if (t < 128) b1_lds[t] = ldf(b1, t, f32m);
  {  // copy 8 KB of W1 fragments: layout identical to w1p (n*512 + lane*8)
    const uint4* src = (const uint4*)w1p;
    uint4* dst = (uint4*)w1_lds;
    dst[t] = src[t];
    dst[t + 256] = src[t + 256];
  }

  short8 ONES;
  { union { u32 u[4]; short8 s; } o;
    o.u[0] = 0x3F803F80u; o.u[1] = 0x3F803F80u;
    o.u[2] = 0x3F803F80u; o.u[3] = 0x3F803F80u; ONES = o.s; }

  __syncthreads();                       // b1_lds / w1_lds ready

  const int nb = w;
  {
    const int n  = n0 + nb;
    const int beg = prow[n];             // 32-aligned by construction
    const int end = beg + deg[n];

    f32x4 accT[8];
    float S8[8];
    f32x4 accH = {0.f, 0.f, 0.f, 0.f};
#pragma unroll
    for (int c = 0; c < 8; ++c) {
      accT[c][0] = 0.f; accT[c][1] = 0.f; accT[c][2] = 0.f; accT[c][3] = 0.f;
      S8[c] = 0.f;
    }

    for (int g = beg; g < end; g += 32) {
      int src_l = (lane < 32) ? srcperm[g + lane] : 0;
      union { u32 u[4]; short8 s; } Ahi, Alo, Amk;
#pragma unroll
      for (int jp = 0; jp < 4; ++jp) {
        const int k0 = q * 8 + 2 * jp, k1 = k0 + 1;
        int s0 = __shfl(src_l, k0);
        int s1 = __shfl(src_l, k1);
        float h0 = hin[(size_t)s0 * 16 + l16];
        float h1 = hin[(size_t)s1 * 16 + l16];
        const int v0 = (g + k0 < end);   // g >= beg always (padded CSR)
        const int v1 = (g + k1 < end);
        h0 = v0 ? h0 : 0.f;
        h1 = v1 ? h1 : 0.f;
        union { float f; u32 u; } b0, b1u; b0.f = h0; b1u.f = h1;
        u32 hi0 = b0.u >> 16, hi1 = b1u.u >> 16;    // truncated bf16 (exact hi)
        union { u32 u; float f; } r0, r1; r0.u = hi0 << 16; r1.u = hi1 << 16;
        u32 lo0 = f2bf(h0 - r0.f), lo1 = f2bf(h1 - r1.f);
        Ahi.u[jp] = hi0 | (hi1 << 16);
        Alo.u[jp] = lo0 | (lo1 << 16);
        Amk.u[jp] = (v0 ? 0x3F80u : 0u) | (v1 ? 0x3F800000u : 0u);
      }

      // stage-A A-fragments straight from global (L2-resident eap)
      short8 ea0 = z8, ea1 = z8;
      if (q < 2) {
        ea0 = *(const short8*)(eap + (size_t)(g + l16) * 16 + q * 8);
        ea1 = *(const short8*)(eap + (size_t)(g + 16 + l16) * 16 + q * 8);
      }

#pragma unroll
      for (int c = 0; c < 8; ++c) {
        short8 Wf = *(const short8*)&w1_lds[c * 512 + lane * 8];
        // A2[slot][c*16+l16] for this chunk (bit-identical to R6's a2pk)
        f32x4 ca = {0.f, 0.f, 0.f, 0.f}, cb = {0.f, 0.f, 0.f, 0.f};
        ca = __builtin_amdgcn_mfma_f32_16x16x32_bf16(ea0, Wf, ca, 0, 0, 0);
        cb = __builtin_amdgcn_mfma_f32_16x16x32_bf16(ea1, Wf, cb, 0, 0, 0);
        float bb = b1_lds[c * 16 + l16];
        u32 p00 = (u32)f2bf(fmaxf(ca[0] + bb, 0.f)) |
                  ((u32)f2bf(fmaxf(ca[1] + bb, 0.f)) << 16);
        u32 p01 = (u32)f2bf(fmaxf(ca[2] + bb, 0.f)) |
                  ((u32)f2bf(fmaxf(ca[3] + bb, 0.f)) << 16);
        u32 p10 = (u32)f2bf(fmaxf(cb[0] + bb, 0.f)) |
                  ((u32)f2bf(fmaxf(cb[1] + bb, 0.f)) << 16);
        u32 p11 = (u32)f2bf(fmaxf(cb[2] + bb, 0.f)) |
                  ((u32)f2bf(fmaxf(cb[3] + bb, 0.f)) << 16);
        // bounce: BB[col][p] = pack(A2[2p][col], A2[2p+1][col])
        u32* bw = &BB_lds[w][l16 * 20];
        uint2 w0; w0.x = p00; w0.y = p01;
        uint2 w1v; w1v.x = p10; w1v.y = p11;
        *(uint2*)&bw[q * 2]     = w0;     // slot pairs q*2, q*2+1   (s 0-15)
        *(uint2*)&bw[8 + q * 2] = w1v;    // slot pairs 8+q*2, +1    (s 16-31)
        // B-fragment read: lane(q,l16): slots q*8..q*8+7 at this col
        short8 Bf = *(const short8*)&bw[q * 4];
        accT[c] = __builtin_amdgcn_mfma_f32_16x16x32_bf16(Ahi.s, Bf, accT[c], 0, 0, 0);
        accT[c] = __builtin_amdgcn_mfma_f32_16x16x32_bf16(Alo.s, Bf, accT[c], 0, 0, 0);
        f32x4 cs = {0.f, 0.f, 0.f, 0.f};
        cs = __builtin_amdgcn_mfma_f32_16x16x32_bf16(Amk.s, Bf, cs, 0, 0, 0);
        S8[c] += cs[0];
      }
      accH = __builtin_amdgcn_mfma_f32_16x16x32_bf16(Ahi.s, ONES, accH, 0, 0, 0);
      accH = __builtin_amdgcn_mfma_f32_16x16x32_bf16(Alo.s, ONES, accH, 0, 0, 0);
    }

    // ---- dump T (bf16, swizzled), S (bf16), hs (f32) to LDS ----
    {
      char* Tl = (char*)T_lds;
#pragma unroll
      for (int c = 0; c < 8; ++c) {
        // lane (q,l16) holds T[k = q*4+r][j = c*16+l16] in accT[c][r]
        u32 p0 = (u32)f2bf(accT[c][0]) | ((u32)f2bf(accT[c][1]) << 16);
        u32 p1 = (u32)f2bf(accT[c][2]) | ((u32)f2bf(accT[c][3]) << 16);
        int b   = (c * 16 + l16) * 32 + q * 8;
        int key = ((nb ^ (c * 8 + (l16 >> 1))) & 7) << 4;
        uint2 pv; pv.x = p0; pv.y = p1;
        *(uint2*)(Tl + (size_t)nb * 4096 + (b ^ key)) = pv;
      }
      if (q == 0) {
        u16* s16 = (u16*)S_lds;
#pragma unroll
        for (int c = 0; c < 8; ++c)
          s16[nb * 128 + c * 16 + l16] = f2bf(S8[c]);
      }
      if (l16 == 0) *(f32x4*)&hs_lds[nb * 16 + q * 4] = accH;
    }
  }
  __syncthreads();

  // GEMM1 (src half): out_src[16n,16d] += T[n][kj] * w2q[kj][d], K=2048
  // wave w owns kc = w*16 .. w*16+15; only node rows 0..3 valid
  const int row = l16;
  f32x4 c1 = {0.f, 0.f, 0.f, 0.f};
  {
    const short8* w2qf = (const short8*)w2q;
#pragma unroll
    for (int kk = 0; kk < 16; ++kk) {
      int kc = w * 16 + kk;
      int off = ((row & 3) * 4096 + kc * 64 + q * 16) ^ ((((row ^ kc) & 7)) << 4);
      short8 af = *(const short8*)((const char*)T_lds + off);
      if (row >= 4) af = z8;
      short8 bf = w2qf[kc * 64 + lane];
      c1 = __builtin_amdgcn_mfma_f32_16x16x32_bf16(af, bf, c1, 0, 0, 0);
    }
  }
  // GEMM2 (dst half): VS[16n, ct*16+d] = S[n][j] * w2d; wave w owns ct=w*4..+3
  f32x4 c2_0 = {0,0,0,0}, c2_1 = {0,0,0,0}, c2_2 = {0,0,0,0}, c2_3 = {0,0,0,0};
  {
    short8 as0, as1, as2, as3;
    {
      const u32* sb = S_lds + (row & 3) * 64 + q * 4;
      as0 = *(const short8*)(sb + 0);
      as1 = *(const short8*)(sb + 16);
      as2 = *(const short8*)(sb + 32);
      as3 = *(const short8*)(sb + 48);
      if (row >= 4) { as0 = z8; as1 = z8; as2 = z8; as3 = z8; }
    }
    const short8* w2df = (const short8*)w2d;
#pragma unroll
    for (int ci = 0; ci < 4; ++ci) {
      int ct = w * 4 + ci;
      f32x4 cc = {0.f, 0.f, 0.f, 0.f};
      cc = __builtin_amdgcn_mfma_f32_16x16x32_bf16(as0, w2df[(ct * 4 + 0) * 64 + lane], cc, 0, 0, 0);
      cc = __builtin_amdgcn_mfma_f32_16x16x32_bf16(as1, w2df[(ct * 4 + 1) * 64 + lane], cc, 0, 0, 0);
      cc = __builtin_amdgcn_mfma_f32_16x16x32_bf16(as2, w2df[(ct * 4 + 2) * 64 + lane], cc, 0, 0, 0);
      cc = __builtin_amdgcn_mfma_f32_16x16x32_bf16(as3, w2df[(ct * 4 + 3) * 64 + lane], cc, 0, 0, 0);
      if (ci == 0) c2_0 = cc; else if (ci == 1) c2_1 = cc;
      else if (ci == 2) c2_2 = cc; else c2_3 = cc;
    }
  }
  // fold dst half: out_dst[n,d] = sum_ct h[n,ct] * VS[n, ct*16+d]
#pragma unroll
  for (int r = 0; r < 4; ++r) {
    int nrow = q * 4 + r;
    const float* hp = h_lds + (nrow & 3) * 16 + w * 4;
    float a = c1[r];
    a += hp[0] * c2_0[r];
    a += hp[1] * c2_1[r];
    a += hp[2] * c2_2[r];
    a += hp[3] * c2_3[r];
    part_lds[w * 256 + nrow * 16 + l16] = a;
  }
  __syncthreads();

  if (t < 64) {
    int nb2 = t >> 4, d = t & 15;
    int n = n0 + nb2;
    float acc = part_lds[nb2 * 16 + d] + part_lds[256 + nb2 * 16 + d] +
                part_lds[512 + nb2 * 16 + d] + part_lds[768 + nb2 * 16 + d];
    float dg = (float)deg[n];
    acc += ldf(bias, d, f32m);
#pragma unroll
    for (int k = 0; k < 16; ++k) {
      float hv = h_lds[nb2 * 16 + k];
      acc += hv * (ldf(root, (size_t)k * 16 + d, f32m) +
                   dg * ldf(b2, (size_t)k * 16 + d, f32m));
      acc += hs_lds[nb2 * 16 + k] * ldf(b2, (size_t)256 + k * 16 + d, f32m);
    }
    if (hout) hout[(size_t)n * 16 + d] = acc;
    else      stf(out, (size_t)n * 16 + d, acc, f32m);
  }
}

// --- OLD fused edge kernel (fallback path) --------------------------------
__launch_bounds__(256, 2)
__global__ void k_edge(const void* __restrict__ ea, const void* __restrict__ ei,
                       const float* __restrict__ hprev,
                       const u16* __restrict__ w2p, const u16* __restrict__ w1p,
                       const void* __restrict__ b1, const void* __restrict__ b2,
                       u16* __restrict__ msg16, float* __restrict__ aggr,
                       const int* __restrict__ inv,
                       const int* __restrict__ flags, int use_csr) {
  __shared__ u16   a2_lds[128 * 136];
  __shared__ float nfT[32 * 132];
  __shared__ float msg_lds[128 * 17];
  __shared__ float b1_lds[128];
  __shared__ int   dst_lds[128];

  const int f32m = flags[0], i64m = !flags[1];
  const int t = threadIdx.x;
  const int lane = t & 63, w = t >> 6;
  const int q = lane >> 4, l16 = lane & 15;
  const int e0 = blockIdx.x * 128;

  short8 B[8][4];
  {
    const short8* w2pf = (const short8*)w2p;
#pragma unroll
    for (int i = 0; i < 8; ++i)
#pragma unroll
      for (int ks = 0; ks < 4; ++ks)
        B[i][ks] = w2pf[((w * 8 + i) * 4 + ks) * 64 + lane];
  }
  float b2v[8];
#pragma unroll
  for (int i = 0; i < 8; ++i) b2v[i] = ldf(b2, (w * 8 + i) * 16 + l16, f32m);
  short8 W1f[8];
  {
    const short8* w1pf = (const short8*)w1p;
#pragma unroll
    for (int n = 0; n < 8; ++n) W1f[n] = w1pf[n * 64 + lane];
  }
  if (t < 128) b1_lds[t] = ldf(b1, t, f32m);

  {
    int e = t >> 1, hh = t & 1;
    int node = hh ? ldi(ei, e0 + e, i64m) : ldi(ei, NE + e0 + e, i64m);
    const float4* hp = (const float4*)(hprev + (size_t)node * 16);
    float4 h0v = hp[0], h1v = hp[1], h2v = hp[2], h3v = hp[3];
    float* col = nfT + (size_t)(hh * 16) * 132 + e;
    col[0 * 132] = h0v.x; col[1 * 132] = h0v.y; col[2 * 132] = h0v.z; col[3 * 132] = h0v.w;
    col[4 * 132] = h1v.x; col[5 * 132] = h1v.y; col[6 * 132] = h1v.z; col[7 * 132] = h1v.w;
    col[8 * 132] = h2v.x; col[9 * 132] = h2v.y; col[10 * 132] = h2v.z; col[11 * 132] = h2v.w;
    col[12 * 132] = h3v.x; col[13 * 132] = h3v.y; col[14 * 132] = h3v.z; col[15 * 132] = h3v.w;
    if (!hh) {
      if (use_csr) dst_lds[e] = inv[e0 + e];
      else         dst_lds[e] = node;
    }
    float* mz = msg_lds + e * 17 + hh * 8;
#pragma unroll
    for (int k2 = 0; k2 < 8; ++k2) mz[k2] = 0.f;
  }
  __syncthreads();

#pragma unroll
  for (int mm = 0; mm < 2; ++mm) {
    int m = w * 2 + mm;
    union { short8 s; u16 h[8]; } ua;
    if (q < 2) {
      if (f32m) {
        const float* er = (const float*)ea + ((size_t)(e0 + m * 16 + l16) * 16 + q * 8);
        float4 f0 = *(const float4*)er;
        float4 f1 = *(const float4*)(er + 4);
        ua.h[0] = f2bf(f0.x); ua.h[1] = f2bf(f0.y); ua.h[2] = f2bf(f0.z); ua.h[3] = f2bf(f0.w);
        ua.h[4] = f2bf(f1.x); ua.h[5] = f2bf(f1.y); ua.h[6] = f2bf(f1.z); ua.h[7] = f2bf(f1.w);
      } else {
        ua.s = *(const short8*)((const u16*)ea + ((size_t)(e0 + m * 16 + l16) * 16 + q * 8));
      }
    } else {
#pragma unroll
      for (int j = 0; j < 8; ++j) ua.h[j] = 0;
    }
    short8 A = ua.s;
#pragma unroll
    for (int n = 0; n < 8; ++n) {
      f32x4 c = {0.f, 0.f, 0.f, 0.f};
      c = __builtin_amdgcn_mfma_f32_16x16x32_bf16(A, W1f[n], c, 0, 0, 0);
      float bb = b1_lds[n * 16 + l16];
#pragma unroll
      for (int r = 0; r < 4; ++r)
        a2_lds[(m * 16 + q * 4 + r) * 136 + n * 16 + l16] =
            f2bf(fmaxf(c[r] + bb, 0.f));
    }
  }
  __syncthreads();

#pragma unroll 1
  for (int mi = 0; mi < 8; ++mi) {
    int m = (mi + w * 2) & 7;
    const short8* ap = (const short8*)&a2_lds[(m * 16 + l16) * 136 + q * 8];
    short8 A0 = ap[0], A1 = ap[4], A2f = ap[8], A3 = ap[12];
    float mr0 = 0.f, mr1 = 0.f, mr2 = 0.f, mr3 = 0.f;
#pragma unroll
    for (int i = 0; i < 8; ++i) {
      f32x4 c = {b2v[i], b2v[i], b2v[i], b2v[i]};
      c = __builtin_amdgcn_mfma_f32_16x16x32_bf16(A0, B[i][0], c, 0, 0, 0);
      c = __builtin_amdgcn_mfma_f32_16x16x32_bf16(A1, B[i][1], c, 0, 0, 0);
      c = __builtin_amdgcn_mfma_f32_16x16x32_bf16(A2f, B[i][2], c, 0, 0, 0);
      c = __builtin_amdgcn_mfma_f32_16x16x32_bf16(A3, B[i][3], c, 0, 0, 0);
      int kb = w * 8 + i;
      f32x4 nf4 = *(const f32x4*)&nfT[(size_t)kb * 132 + m * 16 + q * 4];
      mr0 += nf4[0] * c[0];
      mr1 += nf4[1] * c[1];
      mr2 += nf4[2] * c[2];
      mr3 += nf4[3] * c[3];
    }
    int eb = (m * 16 + q * 4) * 17 + l16;
    atomicAdd(&msg_lds[eb + 0 * 17], mr0);
    atomicAdd(&msg_lds[eb + 1 * 17], mr1);
    atomicAdd(&msg_lds[eb + 2 * 17], mr2);
    atomicAdd(&msg_lds[eb + 3 * 17], mr3);
  }
  __syncthreads();

  {
    int e = t >> 1, dh = t & 1;
    const float* mp = msg_lds + e * 17 + dh * 8;
    if (use_csr) {
      int pos = dst_lds[e];
      union { uint4 qv; u16 h[8]; } pk;
#pragma unroll
      for (int dd = 0; dd < 8; ++dd) pk.h[dd] = f2bf(mp[dd]);
      *(uint4*)(msg16 + (size_t)pos * 16 + dh * 8) = pk.qv;
    } else {
      int dnode = dst_lds[e];
      float* ap2 = aggr + (size_t)dnode * 16 + dh * 8;
#pragma unroll
      for (int dd = 0; dd < 8; ++dd) atomicAdd(ap2 + dd, mp[dd]);
    }
  }
}

// --- gather + combine (fallback path) -------------------------------------
__global__ void k_gather(const u16* __restrict__ msg16,
                         const int* __restrict__ rowptr,
                         const float* __restrict__ h_old,
                         const void* __restrict__ root,
                         const void* __restrict__ bias,
                         float* __restrict__ h_new, void* __restrict__ out,
                         const int* __restrict__ flags) {
  const int f32m = flags[0];
  __shared__ float R[256];
  __shared__ float Bv[16];
  int tt = threadIdx.x;
  R[tt] = ldf(root, tt, f32m);
  if (tt < 16) Bv[tt] = ldf(bias, tt, f32m);
  __syncthreads();
  int t = blockIdx.x * 256 + tt;
  if (t >= NN * 16) return;
  int n = t >> 4, d = t & 15;
  float acc = Bv[d];
#pragma unroll
  for (int k = 0; k < 16; ++k) acc += h_old[n * 16 + k] * R[k * 16 + d];
  int beg = rowptr[n], end = rowptr[n + 1];
  for (int i = beg; i < end; ++i)
    acc += bf2f(msg16[(size_t)i * 16 + d]);
  if (h_new) h_new[t] = acc;
  else       stf(out, t, acc, f32m);
}

// --- fallback combine (non-CSR path) --------------------------------------
__global__ void k_combine(const float* __restrict__ h_old,
                          const float* __restrict__ aggr,
                          const void* __restrict__ root,
                          const void* __restrict__ bias,
                          float* __restrict__ h_new, void* __restrict__ out,
                          const int* __restrict__ flags) {
  const int f32m = flags[0];
  int t = blockIdx.x * 256 + threadIdx.x;
  if (t >= NN * 16) return;
  int n = t >> 4, d = t & 15;
  float acc = aggr[t] + ldf(bias, d, f32m);
  for (int k = 0; k < 16; ++k)
    acc += h_old[n * 16 + k] * ldf(root, (size_t)k * 16 + d, f32m);
  if (h_new) h_new[t] = acc;
  else       stf(out, t, acc, f32m);
}

// --- edge embedding + log_softmax (fallback path) -------------------------
__global__ void k_ee(const void* __restrict__ ea, const void* __restrict__ We,
                     const void* __restrict__ be, void* __restrict__ out,
                     const int* __restrict__ flags) {
  const int f32m = flags[0];
  __shared__ float W[256];
  __shared__ float Bv[16];
  int t = threadIdx.x;
  W[t] = ldf(We, t, f32m);
  if (t < 16) Bv[t] = ldf(be, t, f32m);
  __syncthreads();
  int e = blockIdx.x * 256 + t;
  if (e >= NE) return;
  float v[16];
  if (f32m) {
    const float4* ep = (const float4*)((const float*)ea + (size_t)e * 16);
    float4 r0 = ep[0], r1 = ep[1], r2 = ep[2], r3 = ep[3];
    v[0]=r0.x; v[1]=r0.y; v[2]=r0.z; v[3]=r0.w;
    v[4]=r1.x; v[5]=r1.y; v[6]=r1.z; v[7]=r1.w;
    v[8]=r2.x; v[9]=r2.y; v[10]=r2.z; v[11]=r2.w;
    v[12]=r3.x; v[13]=r3.y; v[14]=r3.z; v[15]=r3.w;
  } else {
    union { uint4 qv[2]; u16 h[16]; } rw;
    const uint4* ep = (const uint4*)((const u16*)ea + (size_t)e * 16);
    rw.qv[0] = ep[0]; rw.qv[1] = ep[1];
#pragma unroll
    for (int k = 0; k < 16; ++k) v[k] = bf2f(rw.h[k]);
  }
  float o[16];
  float mx = 0.f;
#pragma unroll
  for (int d = 0; d < 16; ++d) {
    float acc = Bv[d];
#pragma unroll
    for (int k = 0; k < 16; ++k) acc += v[k] * W[k * 16 + d];
    acc = fmaxf(acc, 0.f);
    o[d] = acc;
    mx = fmaxf(mx, acc);
  }
  float s = 0.f;
#pragma unroll
  for (int d = 0; d < 16; ++d) s += __expf(o[d] - mx);
  float lse = mx + __logf(s);
  const size_t off_ee = 1120000, off_ls = 7520000;
  if (f32m) {
    union { float4 fv; float f[4]; } pe, pl;
    float* oe = (float*)out + off_ee + (size_t)e * 16;
    float* ol = (float*)out + off_ls + (size_t)e * 16;
#pragma unroll
    for (int g = 0; g < 4; ++g) {
#pragma unroll
      for (int d = 0; d < 4; ++d) { pe.f[d] = o[g*4+d]; pl.f[d] = o[g*4+d] - lse; }
      ((float4*)oe)[g] = pe.fv;
      ((float4*)ol)[g] = pl.fv;
    }
  } else {
    union { uint4 qv[2]; u16 h[16]; } pe, pl;
#pragma unroll
    for (int d = 0; d < 16; ++d) {
      pe.h[d] = f2bf(o[d]);
      pl.h[d] = f2bf(o[d] - lse);
    }
    uint4* oe = (uint4*)((u16*)out + off_ee + (size_t)e * 16);
    uint4* ol = (uint4*)((u16*)out + off_ls + (size_t)e * 16);
    oe[0] = pe.qv[0]; oe[1] = pe.qv[1];
    ol[0] = pl.qv[0]; ol[1] = pl.qv[1];
  }
}

// --- edge_index passthrough (fallback path) -------------------------------
__global__ void k_idx(const void* __restrict__ ei, void* __restrict__ out,
                      const int* __restrict__ flags) {
  const int f32m = flags[0], i64m = !flags[1];
  int i = blockIdx.x * 256 + threadIdx.x;
  if (i >= 2 * NE) return;
  float v = i64m ? (float)((const long long*)ei)[i] : (float)((const int*)ei)[i];
  stf(out, (size_t)320000 + i, v, f32m);
}

extern "C" void kernel_launch(void* const* d_in, const int* in_sizes, int n_in,
                              void* d_out, int out_size, void* d_ws, size_t ws_size,
                              hipStream_t stream) {
  const void* x     = d_in[0];
  const void* ei    = d_in[1];
  const void* ea    = d_in[2];
  const void* Wn    = d_in[3];
  const void* bn    = d_in[4];
  const void* We    = d_in[5];
  const void* be    = d_in[6];
  const void* W1    = d_in[7];
  const void* b1    = d_in[8];
  const void* W2    = d_in[9];
  const void* b2    = d_in[10];
  const void* root1 = d_in[11];
  const void* bias1 = d_in[12];
  const void* root2 = d_in[13];
  const void* bias2 = d_in[14];

  char* ws = (char*)d_ws;
  const size_t need_new = 39659296;

  if (ws_size >= need_new) {
    int*   flags   = (int*)ws;                        // @0          16
    int*   deg     = (int*)(ws + 16);                 // 80,000 (memset with flags)
    float* h0      = (float*)(ws + 80016);            // 1,280,000
    float* h1      = (float*)(ws + 1360016);          // 1,280,000
    u16*   w1p     = (u16*)(ws + 2640016);            // 8,192
    u16*   w2q     = (u16*)(ws + 2648208);            // 65,536
    u16*   w2d     = (u16*)(ws + 2713744);            // 65,536
    int*   prow    = (int*)(ws + 2779280);            // 80,016
    int*   cursor  = (int*)(ws + 2859296);            // 80,000
    int*   srcperm = (int*)(ws + 2939296);            // 4,080,000 (1.02M slots)
    u16*   eap     = (u16*)(ws + 7019296);            // 32,640,000

    hipMemsetAsync(ws, 0, 80016, stream);             // flags + deg
    hipMemsetAsync(srcperm, 0, 36720000, stream);     // srcperm + eap (pad slots)
    k_detect<<<128, 256, 0, stream>>>((const u16*)x, (const int*)ei, flags);
    k_misc<<<7535, 256, 0, stream>>>(W1, w1p, W2, w2q, w2d, x, Wn, bn, h0,
                                     ei, deg, ea, We, be, d_out, flags);
    k_scanp<<<1, 1024, 0, stream>>>(deg, prow, cursor);
    k_scatter<<<1563, 256, 0, stream>>>(ei, cursor, nullptr, srcperm, ea, eap, flags);

    k_node<<<5000, 256, 0, stream>>>(prow, deg, srcperm, eap, h0, w1p, b1,
                                     w2q, w2d, b2, root1, bias1, h1, nullptr, flags);
    k_node<<<5000, 256, 0, stream>>>(prow, deg, srcperm, eap, h1, w1p, b1,
                                     w2q, w2d, b2, root2, bias2, nullptr, d_out, flags);
    return;
  }

  // ---------------- fallback: previous-session pipeline -------------------
  int*   flags  = (int*)ws;                              // @0, 16 B
  float* h0     = (float*)(ws + 16);                     // 1,280,000 B
  float* h1     = (float*)(ws + 1280016);                // 1,280,000 B
  u16*   w2p    = (u16*)(ws + 2560016);                  //   131,072 B
  u16*   w1p    = (u16*)(ws + 2691088);                  //     8,192 B
  u16*   msg16  = (u16*)(ws + 2699280);                  // 12,800,000 B
  int*   rowptr = (int*)(ws + 15499280);                 //     80,016 B
  int*   cursor = (int*)(ws + 15579296);                 //     80,000 B
  int*   inv    = (int*)(ws + 15659296);                 //  1,600,000 B
  const size_t need_csr = 17259296;
  float* aggr = (float*)(ws + 2699280);                  // aliases msg16
  const int use_csr = (ws_size >= need_csr) ? 1 : 0;

  hipMemsetAsync(flags, 0, 16, stream);
  k_detect<<<64, 256, 0, stream>>>((const u16*)x, (const int*)ei, flags);
  k_pack_w2<<<32, 256, 0, stream>>>(W2, w2p, flags);
  k_pack_w1<<<2, 256, 0, stream>>>(W1, w1p, flags);
  k_embed<<<1250, 256, 0, stream>>>(x, Wn, bn, h0, flags);

  if (use_csr) {
    hipMemsetAsync(cursor, 0, NN * 4, stream);
    k_count<<<1563, 256, 0, stream>>>(ei, cursor, flags);
    k_scan<<<1, 1024, 0, stream>>>(cursor, rowptr, cursor);
    k_scatter<<<1563, 256, 0, stream>>>(ei, cursor, inv, nullptr, nullptr, nullptr, flags);

    k_edge<<<3125, 256, 0, stream>>>(ea, ei, h0, w2p, w1p, b1, b2, msg16, nullptr, inv, flags, 1);
    k_gather<<<1250, 256, 0, stream>>>(msg16, rowptr, h0, root1, bias1, h1, nullptr, flags);
    k_edge<<<3125, 256, 0, stream>>>(ea, ei, h1, w2p, w1p, b1, b2, msg16, nullptr, inv, flags, 1);
    k_gather<<<1250, 256, 0, stream>>>(msg16, rowptr, h1, root2, bias2, nullptr, d_out, flags);
  } else {
    hipMemsetAsync(aggr, 0, (size_t)NN * 16 * 4, stream);
    k_edge<<<3125, 256, 0, stream>>>(ea, ei, h0, w2p, w1p, b1, b2, nullptr, aggr, nullptr, flags, 0);
    k_combine<<<1250, 256, 0, stream>>>(h0, aggr, root1, bias1, h1, nullptr, flags);
    hipMemsetAsync(aggr, 0, (size_t)NN * 16 * 4, stream);
    k_edge<<<3125, 256, 0, stream>>>(ea, ei, h1, w2p, w1p, b1, b2, nullptr, aggr, nullptr, flags, 0);
    k_combine<<<1250, 256, 0, stream>>>(h1, aggr, root2, bias2, nullptr, d_out, flags);
  }

  k_ee<<<1563, 256, 0, stream>>>(ea, We, be, d_out, flags);
  k_idx<<<3125, 256, 0, stream>>>(ei, d_out, flags);
}